// Round 8
// baseline (198.901 us; speedup 1.0000x reference)
//
#include <hip/hip_runtime.h>
#include <math.h>

namespace {

constexpr int W_TS = 256, NE = 16, NB = 512, NI = 10, NF = 3;
constexpr int BI   = NB * NI;          // 5120
constexpr int PROJ = 7, IN_P = 4, EMB = 32, NTOT = 79;
constexpr int CH   = 64;               // chains per block
constexpr int NW   = 4;                // waves per block
constexpr int BLK  = CH * NW / 16;     // dummy avoid; real BLK below
constexpr int BLOCK_THREADS = 256;     // 4 waves x 64 lanes
constexpr int TCH  = 16;               // timesteps per chunk
constexpr int NCH  = W_TS / TCH;       // 16 chunks; wave w owns chunks w, w+4, w+8, w+12
constexpr float MAX_RATIO    = 0.5f;
constexpr float INV_SQRT_DEG = 0.70710678118654752440f;
constexpr size_t TS_IN  = (size_t)NE * BI * NF;   // floats per timestep (input)
constexpr size_t TS_OUT = (size_t)NE * BI;        // floats per timestep (output)

struct F3 { float x, y, z; };          // 12B, 4B-aligned

__device__ __forceinline__ float gelu_exact(float x) {
  return 0.5f * x * (1.0f + erff(x * 0.70710678118654752440f));
}

template<int N, int OB>
__device__ __forceinline__ void constrain_group(
    const float* __restrict__ Wo, const float* __restrict__ bo,
    const float* __restrict__ h1, const float* __restrict__ refw,
    float* __restrict__ outw)
{
  float off[N];
  float ss = 0.f;
#pragma unroll
  for (int n = 0; n < N; ++n) {
    float acc = bo[OB + n];
#pragma unroll
    for (int i = 0; i < EMB; ++i)
      acc = fmaf(Wo[(OB + n) * EMB + i], h1[i], acc);
    off[n] = acc;
    ss = fmaf(acc, acc, ss);
  }
  float rn = 0.f;
#pragma unroll
  for (int n = 0; n < N; ++n) { float w = refw[n]; rn = fmaf(w, w, rn); }
  float max_norm = fmaxf(sqrtf(rn) * MAX_RATIO, 0.01f);
  float scale    = fminf(max_norm / (sqrtf(ss) + 1e-8f), 1.0f);
#pragma unroll
  for (int n = 0; n < N; ++n) outw[n] = refw[n] + off[n] * scale;
}

__global__ __launch_bounds__(BLOCK_THREADS)
void ensemble_rnn(const float* __restrict__ xin,       // (W_TS,E,BI,F)
                  const float* __restrict__ h0,        // (E,BI)
                  const float* __restrict__ embedding, // (E,NB,EMB)
                  const float* __restrict__ w0g,       // (E,7,4)
                  const float* __restrict__ w1g,       // (E,7,4)
                  const float* __restrict__ b0g,       // (E,7)
                  const float* __restrict__ b1g,       // (E,7)
                  const float* __restrict__ wng,       // (E,1,7)
                  const float* __restrict__ bng,       // (E,1)
                  const float* __restrict__ damping,   // (E)
                  const float* __restrict__ hW_in,     // (E,32,32)
                  const float* __restrict__ hb_in,     // (E,32)
                  const float* __restrict__ hW_out,    // (E,79,32)
                  const float* __restrict__ hb_out,    // (E,79)
                  float* __restrict__ out)             // (W_TS,E,BI)
{
  __shared__ float scoef[15][CH];   // 15 quadratic-form coeffs per chain
  __shared__ float hbuf[CH];        // h token handoff between pipeline stages

  const int tid  = (int)threadIdx.x;
  const int lane = tid & 63;
  const int wid  = tid >> 6;                     // pipeline stage id (0..3)
  constexpr int BLOCKS_PER_E = BI / CH;          // 80 -> e block-uniform
  const int e  = (int)blockIdx.x / BLOCKS_PER_E;
  const int cg = (int)blockIdx.x * CH + lane;    // global chain = e*BI + bi
  const float* xcg = xin + (size_t)cg * NF;

  float xa[TCH][3], xb[TCH][3];

#define LOADCHUNK(X, CI)                                              \
  do {                                                                \
    _Pragma("unroll")                                                 \
    for (int t = 0; t < TCH; ++t) {                                   \
      F3 v = *(const F3*)(xcg + (size_t)((CI) * TCH + t) * TS_IN);    \
      X[t][0] = v.x; X[t][1] = v.y; X[t][2] = v.z;                    \
    }                                                                 \
  } while (0)

  // each wave preloads its FIRST chunk (chunk == wid) before anything else;
  // loads complete under the hypernet compute.
  LOADCHUNK(xa, wid);

  if (wid == 0) {
    // ---------------- hypernetwork (wave 0 only; verified R3 math) ----------
    const int bi = cg - e * BI;
    const int b  = bi / NI;
    float emb[EMB];
    {
      const float4* ep =
          reinterpret_cast<const float4*>(embedding + ((size_t)e * NB + b) * EMB);
#pragma unroll
      for (int i = 0; i < EMB / 4; ++i) {
        float4 v = ep[i];
        emb[4*i+0] = v.x; emb[4*i+1] = v.y; emb[4*i+2] = v.z; emb[4*i+3] = v.w;
      }
    }
    float h1[EMB];
    {
      const float* Wi = hW_in + (size_t)e * EMB * EMB;
      const float* bb = hb_in + (size_t)e * EMB;
#pragma unroll
      for (int o = 0; o < EMB; ++o) {
        float acc = bb[o];
#pragma unroll
        for (int i = 0; i < EMB; ++i) acc = fmaf(Wi[o * EMB + i], emb[i], acc);
        h1[o] = gelu_exact(acc);
      }
    }
    const float* Wo = hW_out + (size_t)e * NTOT * EMB;
    const float* bo = hb_out + (size_t)e * NTOT;

    float w0e[PROJ * IN_P], w1e[PROJ * IN_P];
    float b0e[PROJ], b1e[PROJ], wns[PROJ], bne;

    constrain_group<28, 0 >(Wo, bo, h1, w0g + e * 28, w0e);
    constrain_group<28, 28>(Wo, bo, h1, w1g + e * 28, w1e);
    constrain_group<7,  56>(Wo, bo, h1, b0g + e * 7,  b0e);
    constrain_group<7,  63>(Wo, bo, h1, b1g + e * 7,  b1e);
    constrain_group<7,  70>(Wo, bo, h1, wng + e * 7,  wns);
    constrain_group<1,  77>(Wo, bo, h1, bng + e,      &bne);

    const float dec = 1.0f / (1.0f + expf(-damping[e]));
    const float omd = 1.0f - dec;

    float M[5][5];
#pragma unroll
    for (int i = 0; i < 5; ++i)
#pragma unroll
      for (int j = 0; j < 5; ++j) M[i][j] = 0.f;
#pragma unroll
    for (int o = 0; o < PROJ; ++o) {
      const float s = wns[o] * INV_SQRT_DEG;
      float w0h[5] = { w0e[o*4+0], w0e[o*4+1], w0e[o*4+2], w0e[o*4+3], b0e[o] };
      float w1h[5] = { w1e[o*4+0], w1e[o*4+1], w1e[o*4+2], w1e[o*4+3], b1e[o] };
#pragma unroll
      for (int i = 0; i < 5; ++i) {
        const float t = s * w0h[i];
#pragma unroll
        for (int j = 0; j < 5; ++j) M[i][j] = fmaf(t, w1h[j], M[i][j]);
      }
    }
    scoef[ 0][lane] = M[0][0];
    scoef[ 1][lane] = M[0][1] + M[1][0];
    scoef[ 2][lane] = M[0][2] + M[2][0];
    scoef[ 3][lane] = M[0][3] + M[3][0];
    scoef[ 4][lane] = M[0][4] + M[4][0];
    scoef[ 5][lane] = M[1][1];
    scoef[ 6][lane] = M[1][2] + M[2][1];
    scoef[ 7][lane] = M[1][3] + M[3][1];
    scoef[ 8][lane] = M[1][4] + M[4][1];
    scoef[ 9][lane] = M[2][2];
    scoef[10][lane] = M[2][3] + M[3][2];
    scoef[11][lane] = M[2][4] + M[4][2];
    scoef[12][lane] = M[3][3];
    scoef[13][lane] = M[3][4] + M[4][3] + omd;   // leak folded in
    scoef[14][lane] = M[4][4] + bne;             // bias folded in
  }

  float h = (wid == 0) ? h0[cg] : 0.0f;

  __syncthreads();   // coeffs published

  const float c00 = scoef[ 0][lane], c01 = scoef[ 1][lane], c02 = scoef[ 2][lane];
  const float c03 = scoef[ 3][lane], c04 = scoef[ 4][lane], c11 = scoef[ 5][lane];
  const float c12 = scoef[ 6][lane], c13 = scoef[ 7][lane], c14 = scoef[ 8][lane];
  const float c22 = scoef[ 9][lane], c23 = scoef[10][lane], c24 = scoef[11][lane];
  const float c33 = scoef[12][lane], c34 = scoef[13][lane], c44 = scoef[14][lane];

#define COMPUTE_CHUNK(X, CI)                                          \
  do {                                                                \
    _Pragma("unroll")                                                 \
    for (int k = 0; k < TCH; ++k) {                                   \
      const float x0 = X[k][0], x1 = X[k][1], x2 = X[k][2];           \
      float r0 = fmaf(c00, x0, c04);                                  \
      r0 = fmaf(c01, x1, r0); r0 = fmaf(c02, x2, r0);                 \
      r0 = fmaf(c03, h, r0);                                          \
      float r1 = fmaf(c11, x1, c14);                                  \
      r1 = fmaf(c12, x2, r1); r1 = fmaf(c13, h, r1);                  \
      float r2 = fmaf(c22, x2, c24); r2 = fmaf(c23, h, r2);           \
      float r3 = fmaf(c33, h, c34);                                   \
      float hn = c44;                                                 \
      hn = fmaf(x0, r0, hn); hn = fmaf(x1, r1, hn);                   \
      hn = fmaf(x2, r2, hn); hn = fmaf(h, r3, hn);                    \
      h = hn;                                                         \
      out[(size_t)((CI) * TCH + k) * TS_OUT + cg] = h;                \
    }                                                                 \
  } while (0)

  // Pipeline: slot s -> wave (s&3) computes chunk s; h token via hbuf.
  // Chunk s lives in buffer parity (s/4)&1 (xa for j even, xb for j odd).
  // Prefetch for chunk s+4 issued at the START of the owning wave's active
  // slot -> ~3 slots of latency slack before use.
#define SLOT(S, XCUR, XNXT, DO_PF)                                    \
  do {                                                                \
    if (wid == ((S) & 3)) {                                           \
      if (DO_PF) LOADCHUNK(XNXT, (S) + 4);                            \
      if ((S) > 0) h = hbuf[lane];                                    \
      COMPUTE_CHUNK(XCUR, S);                                         \
      hbuf[lane] = h;                                                 \
    }                                                                 \
    __syncthreads();                                                  \
  } while (0)

  SLOT( 0, xa, xb, true);
  SLOT( 1, xa, xb, true);
  SLOT( 2, xa, xb, true);
  SLOT( 3, xa, xb, true);
  SLOT( 4, xb, xa, true);
  SLOT( 5, xb, xa, true);
  SLOT( 6, xb, xa, true);
  SLOT( 7, xb, xa, true);
  SLOT( 8, xa, xb, true);
  SLOT( 9, xa, xb, true);
  SLOT(10, xa, xb, true);
  SLOT(11, xa, xb, true);
  SLOT(12, xb, xa, false);
  SLOT(13, xb, xa, false);
  SLOT(14, xb, xa, false);
  SLOT(15, xb, xa, false);

#undef SLOT
#undef COMPUTE_CHUNK
#undef LOADCHUNK
}

} // anonymous namespace

extern "C" void kernel_launch(void* const* d_in, const int* in_sizes, int n_in,
                              void* d_out, int out_size, void* d_ws, size_t ws_size,
                              hipStream_t stream) {
  const float* xin  = (const float*)d_in[0];
  const float* h0   = (const float*)d_in[1];
  const float* emb  = (const float*)d_in[2];
  const float* w0   = (const float*)d_in[3];
  const float* w1   = (const float*)d_in[4];
  const float* b0   = (const float*)d_in[5];
  const float* b1   = (const float*)d_in[6];
  const float* wn   = (const float*)d_in[7];
  const float* bn   = (const float*)d_in[8];
  const float* damp = (const float*)d_in[9];
  const float* hWi  = (const float*)d_in[10];
  const float* hbi  = (const float*)d_in[11];
  const float* hWo  = (const float*)d_in[12];
  const float* hbo  = (const float*)d_in[13];
  float* out = (float*)d_out;

  dim3 grid(NE * BI / CH);        // 1280 blocks (64 chains each)
  dim3 block(BLOCK_THREADS);      // 4 waves: pipeline stages over time-chunks
  hipLaunchKernelGGL(ensemble_rnn, grid, block, 0, stream,
                     xin, h0, emb, w0, w1, b0, b1, wn, bn, damp,
                     hWi, hbi, hWo, hbo, out);
}